// Round 21
// baseline (133.549 us; speedup 1.0000x reference)
//
#include <hip/hip_runtime.h>
#include <stdint.h>

#define NPTS 4096
#define SENT NPTS
#define MAXSP 512
#define SCAP 1024          // edge slots per block slice (mean ~240)
#define NSLICE 32          // adj blocks per batch
#define ESLOTS (SCAP*NSLICE) // 32768 slots per batch
#define ECLDS 10752        // dense LDS edge cache entries (43008 B); overflow -> spill

typedef unsigned long long ull;

// ---------------- LDS union-find (union-by-min: root = component min) -------
__device__ __forceinline__ int find_lds(int* p, int x){
  while (true){
    int px = p[x];
    if (px == x) return x;
    int ppx = p[px];
    if (ppx == px) return px;
    p[x] = ppx;            // path halving (benign race; links only decrease)
    x = ppx;
  }
}

__device__ __forceinline__ void union_lds(int* p, int a, int b){
  a = find_lds(p, a);
  b = find_lds(p, b);
  while (a != b){
    int lo = min(a, b), hi = max(a, b);
    int old = atomicCAS(&p[hi], hi, lo);   // LDS CAS
    if (old == hi || old == lo) return;
    a = lo; b = old;                        // old = hi's true parent (< hi)
  }
}

// j>i diagonal mask for word at lane base
__device__ __forceinline__ ull trimask(ull m, int i, int base){
  if (base + 63 <= i) return 0ULL;
  if (base <= i) return m & ((~0ULL) << (i - base + 1));
  return m;
}

// load point g and its sq with XLA-identical rounding.
// contract(off) must live INSIDE the helper (lexically scoped — R14 lesson).
__device__ __forceinline__ float4 loadpt(const float* __restrict__ c, int g){
#pragma clang fp contract(off)
  float x = c[g*3+0], y = c[g*3+1], z = c[g*3+2];
  float sq = ((x*x) + (y*y)) + (z*z);   // round squares, sequential adds
  return make_float4(x, y, z, sq);
}

// ---------------- fused kernel: adjacency + (last block per batch) mega -----
// Phase A (all 32 blocks/batch): LDS-staged balanced triangle adjacency ->
// per-block edge slices + rcnt (plain stores, nothing pre-zeroed).
// Then release-fence + ctr atomicAdd; the block whose ticket ==31 (mod 32)
// — exactly one per batch per call, for ANY ctr start value — acquires and
// runs Phase B (deg/core/UF/labels/border/finalize) in re-aliased LDS.
// LDS: region1 64KB (P -> ec/LAB/corea/pref/wtots/sMost; Bb aliases dead ec)
//    + region2 16KB (sTot/sFire -> par) = 81920 B -> 2 blocks/CU.
__global__ __launch_bounds__(1024, 8) void k_all(const float* __restrict__ coords,
                                                 uint32_t* __restrict__ edges,
                                                 int* __restrict__ scnt,
                                                 int* __restrict__ rcnt,
                                                 uint32_t* __restrict__ spill,
                                                 unsigned int* __restrict__ ctr,
                                                 int* __restrict__ out){
#pragma clang fp contract(off)
  __shared__ float4 R1[NPTS];   // 64 KB
  __shared__ int    R2[NPTS];   // 16 KB
  int tid  = threadIdx.x;
  int wid  = tid >> 6, lane = tid & 63;
  int b     = blockIdx.x >> 5;          // 32 blocks per batch
  int slice = blockIdx.x & 31;
  int u512  = (slice << 4) + wid;       // wave unit in [0,512)
  int i0 = u512 << 2;                   // low rows i0..i0+3   (cover 0..2047)
  int h0 = (NPTS - 4) - i0;             // high rows h0..h0+3  (cover 2048..4095)
  const float* cb = coords + ((size_t)b << 12) * 3;
  if (tid == 0) R2[0] = 0;              // sTot
  // ---- phase A: stage batch into LDS (sq fused, exact rounding) ----
  for (int g = tid; g < NPTS; g += 1024) R1[g] = loadpt(cb, g);
  __syncthreads();
  const float EPS2 = (float)(0.06 * 0.06);   // f64 product -> f32
  int base = lane << 6;
  ull wl[4], wh[4];
  float4 pL[4];
  #pragma unroll
  for (int r = 0; r < 4; ++r){ pL[r] = R1[i0 + r]; wl[r] = 0ULL; }
  // group 0: low rows, words i0>>6 .. 63
  {
    int W = i0 >> 6;
    for (int k = W; k < 64; ++k){
      float4 cur = R1[(k << 6) + lane];
      #pragma unroll
      for (int r = 0; r < 4; ++r){
        // dot: ascending-k FMA chain, first product plainly rounded (XLA gebp)
        float dot = __builtin_fmaf(pL[r].z, cur.z,
                    __builtin_fmaf(pL[r].y, cur.y, pL[r].x * cur.x));
        float d2  = __builtin_fmaf(-2.0f, dot, pL[r].w + cur.w); // ==rn(s-rn(2dot))
        ull bal = __ballot(d2 <= EPS2);
        if (lane == k) wl[r] = bal;
      }
    }
  }
  // group 1: high rows (pH/wh init deferred to cut live registers)
  {
    float4 pH[4];
    #pragma unroll
    for (int r = 0; r < 4; ++r){ pH[r] = R1[h0 + r]; wh[r] = 0ULL; }
    int W = h0 >> 6;
    for (int k = W; k < 64; ++k){
      float4 cur = R1[(k << 6) + lane];
      #pragma unroll
      for (int r = 0; r < 4; ++r){
        float dot = __builtin_fmaf(pH[r].z, cur.z,
                    __builtin_fmaf(pH[r].y, cur.y, pH[r].x * cur.x));
        float d2  = __builtin_fmaf(-2.0f, dot, pH[r].w + cur.w);
        ull bal = __ballot(d2 <= EPS2);
        if (lane == k) wh[r] = bal;
      }
    }
  }
  // keep j > i only; per-row j>i counts -> rcnt (plain store, one owner/row)
  int* rc = rcnt + (b << 12);
  #pragma unroll
  for (int r = 0; r < 4; ++r){
    wl[r] = trimask(wl[r], i0 + r, base);
    wh[r] = trimask(wh[r], h0 + r, base);
    int cl = __popcll(wl[r]), ch = __popcll(wh[r]);
    #pragma unroll
    for (int off = 32; off; off >>= 1){
      cl += __shfl_xor(cl, off);
      ch += __shfl_xor(ch, off);
    }
    if (lane == 0){ rc[i0 + r] = cl; rc[h0 + r] = ch; }
  }
  // per-lane count -> wave scan -> block LDS counter (no global atomics)
  int cnt = 0;
  #pragma unroll
  for (int r = 0; r < 4; ++r) cnt += __popcll(wl[r]) + __popcll(wh[r]);
  int incl = cnt;
  #pragma unroll
  for (int off = 1; off < 64; off <<= 1){
    int y = __shfl_up(incl, off);
    if (lane >= off) incl += y;
  }
  int total = __shfl(incl, 63);
  int woff = 0;
  if (lane == 63) woff = atomicAdd(&R2[0], total);
  woff = __shfl(woff, 63);
  __syncthreads();
  if (tid == 0) scnt[(b << 5) + slice] = min(R2[0], SCAP);  // plain store
  int pos = woff + incl - cnt;
  uint32_t* eb = edges + (size_t)b * ESLOTS + slice * SCAP;
  #define EMIT(mm, row) { ull e = (mm); while (e){ int bit = __builtin_ctzll(e); \
      e &= e - 1; if (pos < SCAP) eb[pos] = ((uint32_t)(row) << 12) | (uint32_t)(base + bit); ++pos; } }
  #pragma unroll
  for (int r = 0; r < 4; ++r) EMIT(wl[r], i0 + r)
  #pragma unroll
  for (int r = 0; r < 4; ++r) EMIT(wh[r], h0 + r)
  #undef EMIT
  // ---- ticket: exactly one block per batch fires, for ANY ctr start ----
  __threadfence();                      // release edge/rcnt/scnt stores
  __syncthreads();
  if (tid == 0){
    unsigned int t = atomicAdd(&ctr[b << 6], 1u);   // padded 256B line
    R2[1] = ((t & 31u) == 31u) ? 1 : 0; // 32 consecutive tickets -> one hit
  }
  __syncthreads();
  bool fire = (R2[1] != 0);
  __syncthreads();                      // protect R2[1] before par overwrites
  if (!fire) return;
  __threadfence();                      // acquire other blocks' stores

  // ---- phase B: per-batch mega in re-aliased LDS ----
  int* par = R2;                                        // 16 KB
  uint32_t* ec = (uint32_t*)R1;                         // [0, 43008)
  int* LAB = (int*)((char*)R1 + 43008);                 // 16384 B
  unsigned char* corea = (unsigned char*)R1 + 59392;    // 4096 B
  int* pref = (int*)((char*)R1 + 63488);                // 33 ints
  int* wtots = (int*)((char*)R1 + 63624);               // 16 ints
  int* sMost = (int*)((char*)R1 + 63688);
  int* Bb = (int*)R1;                                   // finalize alias (ec dead)
  const uint32_t* ebb = edges + (size_t)b * ESLOTS;
  uint32_t* sp = spill + (size_t)b * (ESLOTS - ECLDS);
  int t = tid;
  if (t < NSLICE) pref[t + 1] = scnt[(b << 5) + t];
  if (t == 0){ pref[0] = 0; *sMost = -1; }
  for (int s = 0; s < 4; ++s){ int v = (t << 2) + s; par[v] = rc[v]; }  // deg seed
  __syncthreads();
  // Hillis-Steele over 32 slice counts (5 rounds)
  for (int off = 1; off < NSLICE; off <<= 1){
    int v = 0;
    if (t < NSLICE && t >= off) v = pref[t + 1 - off];
    __syncthreads();
    if (t < NSLICE && t >= off) pref[t + 1] += v;
    __syncthreads();
  }
  int ecnt = pref[NSLICE];
  // P1: dense compaction (5-level binary-search slice) + j<i incidence
  for (int d = t; d < ecnt; d += 1024){
    int lo = 0, hi = NSLICE - 1;
    #pragma unroll
    for (int s = 0; s < 5; ++s){
      int mid = (lo + hi) >> 1;
      if (pref[mid + 1] <= d) lo = mid + 1; else hi = mid;
    }
    uint32_t pk = ebb[(lo << 10) + (d - pref[lo])];
    if (d < ECLDS) ec[d] = pk; else sp[d - ECLDS] = pk;
    atomicAdd(&par[pk & 4095], 1);
  }
  __syncthreads();
  // P2: core flags, then reinit par as UF identity
  for (int s = 0; s < 4; ++s){ int v = (t << 2) + s; corea[v] = (par[v] >= 2) ? 1 : 0; }
  __syncthreads();
  for (int s = 0; s < 4; ++s){ int v = (t << 2) + s; par[v] = v; }
  __syncthreads();
  // P3: union core-core edges (single pass; fixed point = component min)
  for (int d = t; d < ecnt; d += 1024){
    uint32_t pk = (d < ECLDS) ? ec[d] : sp[d - ECLDS];
    int u = pk >> 12, v = pk & 4095;
    if (corea[u] && corea[v]) union_lds(par, u, v);
  }
  __syncthreads();
  // P4: base labels (core: root; else SENT)
  for (int s = 0; s < 4; ++s){
    int v = (t << 2) + s;
    LAB[v] = corea[v] ? find_lds(par, v) : SENT;
  }
  __syncthreads();
  // P5: border relax — min core-neighbor root via the same dense edges
  for (int d = t; d < ecnt; d += 1024){
    uint32_t pk = (d < ECLDS) ? ec[d] : sp[d - ECLDS];
    int u = pk >> 12, v = pk & 4095;
    int cu = corea[u], cv = corea[v];
    if (cu && !cv)      atomicMin(&LAB[v], find_lds(par, u));
    else if (cv && !cu) atomicMin(&LAB[u], find_lds(par, v));
  }
  __syncthreads();
  // P6: finalize (noise fill, compact, cap). A aliases par; Bb aliases ec.
  int* A = par;
  for (int s = 0; s < 4; ++s){ int v = (t << 2) + s; A[v] = 0; }
  __syncthreads();
  for (int s = 0; s < 4; ++s){ int l = LAB[(t << 2) + s]; if (l < SENT) atomicAdd(&A[l], 1); }
  __syncthreads();
  // most-common label: per-thread best -> wave shfl-max -> 1 atomic per wave
  {
    int best = -1;
    for (int s = 0; s < 4; ++s){
      int v = (t << 2) + s; int c = A[v];
      if (c > 0) best = max(best, (c << 13) | (4095 - v));  // tie -> smallest label
    }
    #pragma unroll
    for (int off = 32; off; off >>= 1) best = max(best, __shfl_xor(best, off));
    if (lane == 0 && best >= 0) atomicMax(sMost, best);
  }
  __syncthreads();
  int most = (*sMost >= 0) ? (4095 - (*sMost & 8191)) : 0;
  for (int s = 0; s < 4; ++s){ int v = (t << 2) + s; if (LAB[v] == SENT) LAB[v] = most; Bb[v] = 0; }
  __syncthreads();
  for (int s = 0; s < 4; ++s) Bb[LAB[(t << 2) + s]] = 1;
  __syncthreads();
  // presence scan: wave shfl-scan + 16 wave totals -> rank = cumsum-1
  int pv[4]; int ls = 0;
  for (int s = 0; s < 4; ++s){ pv[s] = Bb[(t << 2) + s]; ls += pv[s]; }
  int incl2 = ls;
  #pragma unroll
  for (int off = 1; off < 64; off <<= 1){
    int y = __shfl_up(incl2, off);
    if (lane >= off) incl2 += y;
  }
  if (lane == 63) wtots[wid] = incl2;
  __syncthreads();
  int wbase = 0, ncl = 0;
  #pragma unroll
  for (int w = 0; w < 16; ++w){
    int wt = wtots[w];
    if (w < wid) wbase += wt;
    ncl += wt;
  }
  int run = wbase + incl2 - ls;
  for (int s = 0; s < 4; ++s){ run += pv[s]; Bb[(t << 2) + s] = run - 1; }
  __syncthreads();
  for (int s = 0; s < 4; ++s){ int v = (t << 2) + s; LAB[v] = Bb[LAB[v]]; }
  __syncthreads();
  if (ncl > MAXSP){
    // counts2 over compacted labels (0..ncl-1)
    for (int s = 0; s < 4; ++s) A[(t << 2) + s] = 0;
    __syncthreads();
    for (int s = 0; s < 4; ++s) atomicAdd(&A[LAB[(t << 2) + s]], 1);
    __syncthreads();
    // stable (count, index) rank over PRESENT labels only; absent labels
    // (count 0) occupy the first NPTS-ncl slots of the full argsort.
    for (int v = t; v < ncl; v += 1024){
      int keyv = A[v] * NPTS + v;
      int p = 0;
      for (int u = 0; u < ncl; ++u) p += ((A[u] * NPTS + u) < keyv) ? 1 : 0;
      int full = p + (NPTS - ncl);
      Bb[v] = (full >= NPTS - MAXSP) ? (full - (NPTS - MAXSP)) : 0;
    }
    __syncthreads();
    for (int s = 0; s < 4; ++s){ int v = (t << 2) + s; LAB[v] = Bb[LAB[v]]; }
    __syncthreads();
  }
  int* og = out + (b << 12);
  for (int s = 0; s < 4; ++s){ int v = (t << 2) + s; og[v] = LAB[v]; }
}

// ---------------- launch ----------------------------------------------------
extern "C" void kernel_launch(void* const* d_in, const int* in_sizes, int n_in,
                              void* d_out, int out_size, void* d_ws, size_t ws_size,
                              hipStream_t stream){
  const float* coords = (const float*)d_in[0];
  int* out = (int*)d_out;
  int batches = in_sizes[0] / (NPTS * 3);   // 8

  char* ws = (char*)d_ws;
  size_t off = 0;
  int* scnt = (int*)(ws + off); off += (size_t)batches * NSLICE * sizeof(int);   // 1KB
  int* rcnt = (int*)(ws + off); off += (size_t)batches * NPTS * sizeof(int);     // 128KB
  uint32_t* edges = (uint32_t*)(ws + off); off += (size_t)batches * ESLOTS * sizeof(uint32_t); // 1MB
  uint32_t* spill = (uint32_t*)(ws + off); off += (size_t)batches * (ESLOTS - ECLDS) * sizeof(uint32_t);
  unsigned int* ctr = (unsigned int*)(ws + off); off += (size_t)batches * 64 * sizeof(unsigned int); // 256B/batch; NEVER needs zeroing (mod-32 ticket)

  // single fused kernel: 32 blocks/batch x 1024 threads; last block per
  // batch (mod-32 ticket) runs the mega phase.
  k_all<<<batches * NSLICE, 1024, 0, stream>>>(coords, edges, scnt, rcnt,
                                               spill, ctr, out);
}

// Round 22
// 52.847 us; speedup vs baseline: 2.5271x; 2.5271x over previous
//
#include <hip/hip_runtime.h>
#include <stdint.h>

#define NPTS 4096
#define SENT NPTS
#define MAXSP 512
#define SCAP 1024          // edge slots per k_adj block slice (mean ~240)
#define NSLICE 32          // k_adj blocks per batch
#define ESLOTS (SCAP*NSLICE) // 32768 slots per batch
#define ECACHE 16384       // dense LDS edge cache (64 KB); overflow -> spill

typedef unsigned long long ull;

// ---------------- LDS union-find (union-by-min: root = component min) -------
__device__ __forceinline__ int find_lds(int* p, int x){
  while (true){
    int px = p[x];
    if (px == x) return x;
    int ppx = p[px];
    if (ppx == px) return px;
    p[x] = ppx;            // path halving (benign race; links only decrease)
    x = ppx;
  }
}

__device__ __forceinline__ void union_lds(int* p, int a, int b){
  a = find_lds(p, a);
  b = find_lds(p, b);
  while (a != b){
    int lo = min(a, b), hi = max(a, b);
    int old = atomicCAS(&p[hi], hi, lo);   // LDS CAS
    if (old == hi || old == lo) return;
    a = lo; b = old;                        // old = hi's true parent (< hi)
  }
}

// j>i diagonal mask for word at lane base
__device__ __forceinline__ ull trimask(ull m, int i, int base){
  if (base + 63 <= i) return 0ULL;
  if (base <= i) return m & ((~0ULL) << (i - base + 1));
  return m;
}

// load point g and its sq with XLA-identical rounding.
// contract(off) must live INSIDE the helper (lexically scoped — R14 lesson).
__device__ __forceinline__ float4 loadpt(const float* __restrict__ c, int g){
#pragma clang fp contract(off)
  float x = c[g*3+0], y = c[g*3+1], z = c[g*3+2];
  float sq = ((x*x) + (y*y)) + (z*z);   // round squares, sequential adds
  return make_float4(x, y, z, sq);
}

// ---------------- K1: balanced triangle adjacency, LDS-staged points --------
// (R20-proven) 1024-thread blocks (16 waves/CU), 32 slices/batch. Batch
// points staged ONCE per block into LDS (sq fused) -> k-loop is pure
// ds_read_b128 + VALU. d2 bit-exactly symmetric -> j>i only. Wave = 4 low
// rows + 4 mirror high rows: uniform ~65 k-iters. Per-block slice +
// plain-stored counts -> nothing pre-zeroed, no global atomics.
__global__ __launch_bounds__(1024) void k_adj(const float* __restrict__ coords,
                                              uint32_t* __restrict__ edges,
                                              int* __restrict__ scnt,
                                              int* __restrict__ rcnt){
#pragma clang fp contract(off)
  __shared__ float4 P[NPTS];   // 64 KB staged points (x,y,z,sq)
  __shared__ int sTot;
  int tid  = threadIdx.x;
  int wid  = tid >> 6, lane = tid & 63;
  int b     = blockIdx.x >> 5;          // 32 blocks per batch
  int slice = blockIdx.x & 31;
  int u512  = (slice << 4) + wid;       // wave unit in [0,512)
  int i0 = u512 << 2;                   // low rows i0..i0+3   (cover 0..2047)
  int h0 = (NPTS - 4) - i0;             // high rows h0..h0+3  (cover 2048..4095)
  const float* cb = coords + ((size_t)b << 12) * 3;
  if (tid == 0) sTot = 0;
  // stage batch into LDS (coalesced; sq computed once with exact rounding)
  for (int g = tid; g < NPTS; g += 1024) P[g] = loadpt(cb, g);
  __syncthreads();
  const float EPS2 = (float)(0.06 * 0.06);   // f64 product -> f32
  float4 pL[4], pH[4];
  #pragma unroll
  for (int r = 0; r < 4; ++r){ pL[r] = P[i0 + r]; pH[r] = P[h0 + r]; }
  ull wl[4] = {0,0,0,0}, wh[4] = {0,0,0,0};
  int base = lane << 6;
  // group 0: low rows, words i0>>6 .. 63
  {
    int W = i0 >> 6;
    for (int k = W; k < 64; ++k){
      float4 cur = P[(k << 6) + lane];
      #pragma unroll
      for (int r = 0; r < 4; ++r){
        // dot: ascending-k FMA chain, first product plainly rounded (XLA gebp)
        float dot = __builtin_fmaf(pL[r].z, cur.z,
                    __builtin_fmaf(pL[r].y, cur.y, pL[r].x * cur.x));
        float d2  = __builtin_fmaf(-2.0f, dot, pL[r].w + cur.w); // ==rn(s-rn(2dot))
        ull bal = __ballot(d2 <= EPS2);
        if (lane == k) wl[r] = bal;
      }
    }
  }
  // group 1: high rows, words h0>>6 .. 63
  {
    int W = h0 >> 6;
    for (int k = W; k < 64; ++k){
      float4 cur = P[(k << 6) + lane];
      #pragma unroll
      for (int r = 0; r < 4; ++r){
        float dot = __builtin_fmaf(pH[r].z, cur.z,
                    __builtin_fmaf(pH[r].y, cur.y, pH[r].x * cur.x));
        float d2  = __builtin_fmaf(-2.0f, dot, pH[r].w + cur.w);
        ull bal = __ballot(d2 <= EPS2);
        if (lane == k) wh[r] = bal;
      }
    }
  }
  // keep j > i only; per-row j>i counts -> rcnt (plain store, one owner/row)
  int* rc = rcnt + (b << 12);
  #pragma unroll
  for (int r = 0; r < 4; ++r){
    wl[r] = trimask(wl[r], i0 + r, base);
    wh[r] = trimask(wh[r], h0 + r, base);
    int cl = __popcll(wl[r]), ch = __popcll(wh[r]);
    #pragma unroll
    for (int off = 32; off; off >>= 1){
      cl += __shfl_xor(cl, off);
      ch += __shfl_xor(ch, off);
    }
    if (lane == 0){ rc[i0 + r] = cl; rc[h0 + r] = ch; }
  }
  // per-lane count -> wave scan -> block LDS counter (no global atomics)
  int cnt = 0;
  #pragma unroll
  for (int r = 0; r < 4; ++r) cnt += __popcll(wl[r]) + __popcll(wh[r]);
  int incl = cnt;
  #pragma unroll
  for (int off = 1; off < 64; off <<= 1){
    int y = __shfl_up(incl, off);
    if (lane >= off) incl += y;
  }
  int total = __shfl(incl, 63);
  int woff = 0;
  if (lane == 63) woff = atomicAdd(&sTot, total);
  woff = __shfl(woff, 63);
  __syncthreads();
  if (tid == 0) scnt[(b << 5) + slice] = min(sTot, SCAP);  // plain store
  int pos = woff + incl - cnt;
  uint32_t* eb = edges + (size_t)b * ESLOTS + slice * SCAP;
  #define EMIT(mm, row) { ull e = (mm); while (e){ int bit = __builtin_ctzll(e); \
      e &= e - 1; if (pos < SCAP) eb[pos] = ((uint32_t)(row) << 12) | (uint32_t)(base + bit); ++pos; } }
  #pragma unroll
  for (int r = 0; r < 4; ++r) EMIT(wl[r], i0 + r)
  #pragma unroll
  for (int r = 0; r < 4; ++r) EMIT(wh[r], h0 + r)
  #undef EMIT
}

// ---------------- K2: per-batch mega kernel --------------------------------
// ONE dense compaction pass (global->LDS, 5-level binary-search slice map,
// fused incidence) then UF/labels/border run on LDS-dense edges.
// deg[i] = rcnt[i] + (#edges with col i); core <=> deg >= 2 (MIN_SAMPLES=3;
// self-pair always adjacent). P5 reads core roots from LAB (P4 materialized
// them; core LABs are constant during P5) — no find chains.
__global__ __launch_bounds__(1024) void k_mega(const uint32_t* __restrict__ edges,
                                               const int* __restrict__ scnt,
                                               const int* __restrict__ rcnt,
                                               uint32_t* __restrict__ spill,
                                               int* __restrict__ out){
  __shared__ int par[NPTS];          // deg -> UF parent -> A (counts)
  __shared__ int LAB[NPTS];
  __shared__ int Bb[NPTS];           // presence/ranks
  __shared__ unsigned char corea[NPTS];
  __shared__ uint32_t ec[ECACHE];    // dense edge cache
  __shared__ int pref[NSLICE + 1];   // inclusive slice prefix
  __shared__ int wtots[16];
  __shared__ int sMost;
  int b = blockIdx.x, t = threadIdx.x;
  int wid = t >> 6, lane = t & 63;
  const uint32_t* eb = edges + (size_t)b * ESLOTS;
  const int* rc = rcnt + (b << 12);
  uint32_t* sp = spill + (size_t)b * (ESLOTS - ECACHE);
  if (t < NSLICE) pref[t + 1] = scnt[(b << 5) + t];
  if (t == 0){ pref[0] = 0; sMost = -1; }
  for (int s = 0; s < 4; ++s){ int v = (t << 2) + s; par[v] = rc[v]; }  // coalesced seed
  __syncthreads();
  // Hillis-Steele over 32 slice counts (5 rounds)
  for (int off = 1; off < NSLICE; off <<= 1){
    int v = 0;
    if (t < NSLICE && t >= off) v = pref[t + 1 - off];
    __syncthreads();
    if (t < NSLICE && t >= off) pref[t + 1] += v;
    __syncthreads();
  }
  int cnt = pref[NSLICE];
  // P1: dense compaction (5-level binary-search slice) + j<i incidence
  for (int d = t; d < cnt; d += 1024){
    int lo = 0, hi = NSLICE - 1;
    #pragma unroll
    for (int s = 0; s < 5; ++s){
      int mid = (lo + hi) >> 1;
      if (pref[mid + 1] <= d) lo = mid + 1; else hi = mid;
    }
    uint32_t pk = eb[(lo << 10) + (d - pref[lo])];
    if (d < ECACHE) ec[d] = pk; else sp[d - ECACHE] = pk;
    atomicAdd(&par[pk & 4095], 1);
  }
  __syncthreads();
  // P2: core flags, then reinit par as UF identity
  for (int s = 0; s < 4; ++s){ int v = (t << 2) + s; corea[v] = (par[v] >= 2) ? 1 : 0; }
  __syncthreads();
  for (int s = 0; s < 4; ++s){ int v = (t << 2) + s; par[v] = v; }
  __syncthreads();
  // P3: union core-core edges (single pass over dense LDS edges)
  for (int d = t; d < cnt; d += 1024){
    uint32_t pk = (d < ECACHE) ? ec[d] : sp[d - ECACHE];
    int u = pk >> 12, v = pk & 4095;
    if (corea[u] && corea[v]) union_lds(par, u, v);
  }
  __syncthreads();
  // P4: base labels (core: root; else SENT)
  for (int s = 0; s < 4; ++s){
    int v = (t << 2) + s;
    LAB[v] = corea[v] ? find_lds(par, v) : SENT;
  }
  __syncthreads();
  // P5: border relax — min core-neighbor ROOT read from LAB (no finds:
  // LAB[core] was finalized in P4 and is never written during P5)
  for (int d = t; d < cnt; d += 1024){
    uint32_t pk = (d < ECACHE) ? ec[d] : sp[d - ECACHE];
    int u = pk >> 12, v = pk & 4095;
    int cu = corea[u], cv = corea[v];
    if (cu && !cv)      atomicMin(&LAB[v], LAB[u]);
    else if (cv && !cu) atomicMin(&LAB[u], LAB[v]);
  }
  __syncthreads();
  // P6: finalize (noise fill, compact, cap). A aliases par (UF dead now).
  int* A = par;
  for (int s = 0; s < 4; ++s){ int v = (t << 2) + s; A[v] = 0; }
  __syncthreads();
  for (int s = 0; s < 4; ++s){ int l = LAB[(t << 2) + s]; if (l < SENT) atomicAdd(&A[l], 1); }
  __syncthreads();
  // most-common label: per-thread best -> wave shfl-max -> 1 atomic per wave
  {
    int best = -1;
    for (int s = 0; s < 4; ++s){
      int v = (t << 2) + s; int c = A[v];
      if (c > 0) best = max(best, (c << 13) | (4095 - v));  // tie -> smallest label
    }
    #pragma unroll
    for (int off = 32; off; off >>= 1) best = max(best, __shfl_xor(best, off));
    if (lane == 0 && best >= 0) atomicMax(&sMost, best);
  }
  __syncthreads();
  int most = (sMost >= 0) ? (4095 - (sMost & 8191)) : 0;
  for (int s = 0; s < 4; ++s){ int v = (t << 2) + s; if (LAB[v] == SENT) LAB[v] = most; Bb[v] = 0; }
  __syncthreads();
  for (int s = 0; s < 4; ++s) Bb[LAB[(t << 2) + s]] = 1;
  __syncthreads();
  // presence scan: wave shfl-scan + 16 wave totals -> rank = cumsum-1
  int pv[4]; int ls = 0;
  for (int s = 0; s < 4; ++s){ pv[s] = Bb[(t << 2) + s]; ls += pv[s]; }
  int incl = ls;
  #pragma unroll
  for (int off = 1; off < 64; off <<= 1){
    int y = __shfl_up(incl, off);
    if (lane >= off) incl += y;
  }
  if (lane == 63) wtots[wid] = incl;
  __syncthreads();
  int wbase = 0, ncl = 0;
  #pragma unroll
  for (int w = 0; w < 16; ++w){
    int wt = wtots[w];
    if (w < wid) wbase += wt;
    ncl += wt;
  }
  int run = wbase + incl - ls;
  for (int s = 0; s < 4; ++s){ run += pv[s]; Bb[(t << 2) + s] = run - 1; }
  __syncthreads();
  for (int s = 0; s < 4; ++s){ int v = (t << 2) + s; LAB[v] = Bb[LAB[v]]; }
  __syncthreads();
  if (ncl > MAXSP){
    // counts2 over compacted labels (0..ncl-1)
    for (int s = 0; s < 4; ++s) A[(t << 2) + s] = 0;
    __syncthreads();
    for (int s = 0; s < 4; ++s) atomicAdd(&A[LAB[(t << 2) + s]], 1);
    __syncthreads();
    // stable (count, index) rank over PRESENT labels only; absent labels
    // (count 0) occupy the first NPTS-ncl slots of the full argsort.
    for (int v = t; v < ncl; v += 1024){
      int keyv = A[v] * NPTS + v;
      int p = 0;
      for (int u = 0; u < ncl; ++u) p += ((A[u] * NPTS + u) < keyv) ? 1 : 0;
      int full = p + (NPTS - ncl);
      Bb[v] = (full >= NPTS - MAXSP) ? (full - (NPTS - MAXSP)) : 0;
    }
    __syncthreads();
    for (int s = 0; s < 4; ++s){ int v = (t << 2) + s; LAB[v] = Bb[LAB[v]]; }
    __syncthreads();
  }
  int* og = out + (b << 12);
  for (int s = 0; s < 4; ++s){ int v = (t << 2) + s; og[v] = LAB[v]; }
}

// ---------------- launch ----------------------------------------------------
extern "C" void kernel_launch(void* const* d_in, const int* in_sizes, int n_in,
                              void* d_out, int out_size, void* d_ws, size_t ws_size,
                              hipStream_t stream){
  const float* coords = (const float*)d_in[0];
  int* out = (int*)d_out;
  int batches = in_sizes[0] / (NPTS * 3);   // 8

  char* ws = (char*)d_ws;
  size_t off = 0;
  int* scnt = (int*)(ws + off); off += (size_t)batches * NSLICE * sizeof(int);  // 1KB
  int* rcnt = (int*)(ws + off); off += (size_t)batches * NPTS * sizeof(int);    // 128KB
  uint32_t* edges = (uint32_t*)(ws + off); off += (size_t)batches * ESLOTS * sizeof(uint32_t); // 1MB
  uint32_t* spill = (uint32_t*)(ws + off); off += (size_t)batches * (ESLOTS - ECACHE) * sizeof(uint32_t);

  // K1: balanced triangle adjacency (LDS-staged, 16 waves/CU) -> slices+rcnt
  k_adj<<<batches * NSLICE, 1024, 0, stream>>>(coords, edges, scnt, rcnt);
  // K2: per-batch mega (compact-once/deg/core/UF/labels/border/finalize)
  k_mega<<<batches, 1024, 0, stream>>>(edges, scnt, rcnt, spill, out);
}

// Round 24
// 51.584 us; speedup vs baseline: 2.5890x; 1.0245x over previous
//
#include <hip/hip_runtime.h>
#include <stdint.h>

#define NPTS 4096
#define SENT NPTS
#define MAXSP 512
#define NSLICE 32          // adj blocks per batch
#define ESLOTS 32768       // circular edge window per batch (pow2; cnt ~7.6K)
#define EMASK (ESLOTS-1)
#define ECACHE 16384       // dense LDS edge cache (64 KB); overflow -> spill

typedef unsigned long long ull;

// ---------------- LDS union-find (union-by-min: root = component min) -------
__device__ __forceinline__ int find_lds(int* p, int x){
  while (true){
    int px = p[x];
    if (px == x) return x;
    int ppx = p[px];
    if (ppx == px) return px;
    p[x] = ppx;            // path halving (benign race; links only decrease)
    x = ppx;
  }
}

__device__ __forceinline__ void union_lds(int* p, int a, int b){
  a = find_lds(p, a);
  b = find_lds(p, b);
  while (a != b){
    int lo = min(a, b), hi = max(a, b);
    int old = atomicCAS(&p[hi], hi, lo);   // LDS CAS
    if (old == hi || old == lo) return;
    a = lo; b = old;                        // old = hi's true parent (< hi)
  }
}

// j>i diagonal mask for word at lane base
__device__ __forceinline__ ull trimask(ull m, int i, int base){
  if (base + 63 <= i) return 0ULL;
  if (base <= i) return m & ((~0ULL) << (i - base + 1));
  return m;
}

// load point g and its sq with XLA-identical rounding.
// contract(off) must live INSIDE the helper (lexically scoped — R14 lesson).
__device__ __forceinline__ float4 loadpt(const float* __restrict__ c, int g){
#pragma clang fp contract(off)
  float x = c[g*3+0], y = c[g*3+1], z = c[g*3+2];
  float sq = ((x*x) + (y*y)) + (z*z);   // round squares, sequential adds
  return make_float4(x, y, z, sq);
}

// ---------------- K1: balanced triangle adjacency, LDS-staged points --------
// (R20-proven geometry) 1024-thread blocks, 32/batch. Batch points staged
// ONCE into LDS (sq fused) -> k-loop is pure ds_read + VALU. d2 bit-exactly
// symmetric -> j>i only; wave = 4 low + 4 mirror high rows (uniform ~65
// k-iters). Edges go to a CIRCULAR dense window: one global atomicAdd per
// block on ecnt[b] (arbitrary start value G — never zeroed; pow2 wrap is
// exact for any G). rcnt plain-stored per row (mega derives cnt = sum rcnt).
__global__ __launch_bounds__(1024) void k_adj(const float* __restrict__ coords,
                                              uint32_t* __restrict__ edges,
                                              unsigned int* __restrict__ ecnt,
                                              int* __restrict__ rcnt){
#pragma clang fp contract(off)
  __shared__ float4 P[NPTS];   // 64 KB staged points (x,y,z,sq)
  __shared__ int sTot;
  __shared__ unsigned int sBase;
  int tid  = threadIdx.x;
  int wid  = tid >> 6, lane = tid & 63;
  int b     = blockIdx.x >> 5;          // 32 blocks per batch
  int slice = blockIdx.x & 31;
  int u512  = (slice << 4) + wid;       // wave unit in [0,512)
  int i0 = u512 << 2;                   // low rows i0..i0+3   (cover 0..2047)
  int h0 = (NPTS - 4) - i0;             // high rows h0..h0+3  (cover 2048..4095)
  const float* cb = coords + ((size_t)b << 12) * 3;
  if (tid == 0) sTot = 0;
  // stage batch into LDS (coalesced; sq computed once with exact rounding)
  for (int g = tid; g < NPTS; g += 1024) P[g] = loadpt(cb, g);
  __syncthreads();
  const float EPS2 = (float)(0.06 * 0.06);   // f64 product -> f32
  float4 pL[4], pH[4];
  #pragma unroll
  for (int r = 0; r < 4; ++r){ pL[r] = P[i0 + r]; pH[r] = P[h0 + r]; }
  ull wl[4] = {0,0,0,0}, wh[4] = {0,0,0,0};
  int base = lane << 6;
  // group 0: low rows, words i0>>6 .. 63
  {
    int W = i0 >> 6;
    for (int k = W; k < 64; ++k){
      float4 cur = P[(k << 6) + lane];
      #pragma unroll
      for (int r = 0; r < 4; ++r){
        // dot: ascending-k FMA chain, first product plainly rounded (XLA gebp)
        float dot = __builtin_fmaf(pL[r].z, cur.z,
                    __builtin_fmaf(pL[r].y, cur.y, pL[r].x * cur.x));
        float d2  = __builtin_fmaf(-2.0f, dot, pL[r].w + cur.w); // ==rn(s-rn(2dot))
        ull bal = __ballot(d2 <= EPS2);
        if (lane == k) wl[r] = bal;
      }
    }
  }
  // group 1: high rows, words h0>>6 .. 63
  {
    int W = h0 >> 6;
    for (int k = W; k < 64; ++k){
      float4 cur = P[(k << 6) + lane];
      #pragma unroll
      for (int r = 0; r < 4; ++r){
        float dot = __builtin_fmaf(pH[r].z, cur.z,
                    __builtin_fmaf(pH[r].y, cur.y, pH[r].x * cur.x));
        float d2  = __builtin_fmaf(-2.0f, dot, pH[r].w + cur.w);
        ull bal = __ballot(d2 <= EPS2);
        if (lane == k) wh[r] = bal;
      }
    }
  }
  // keep j > i only; per-row j>i counts -> rcnt (plain store, one owner/row)
  int* rc = rcnt + (b << 12);
  #pragma unroll
  for (int r = 0; r < 4; ++r){
    wl[r] = trimask(wl[r], i0 + r, base);
    wh[r] = trimask(wh[r], h0 + r, base);
    int cl = __popcll(wl[r]), ch = __popcll(wh[r]);
    #pragma unroll
    for (int off = 32; off; off >>= 1){
      cl += __shfl_xor(cl, off);
      ch += __shfl_xor(ch, off);
    }
    if (lane == 0){ rc[i0 + r] = cl; rc[h0 + r] = ch; }
  }
  // per-lane count -> wave scan -> block total -> ONE global atomic ticket
  int cnt = 0;
  #pragma unroll
  for (int r = 0; r < 4; ++r) cnt += __popcll(wl[r]) + __popcll(wh[r]);
  int incl = cnt;
  #pragma unroll
  for (int off = 1; off < 64; off <<= 1){
    int y = __shfl_up(incl, off);
    if (lane >= off) incl += y;
  }
  int total = __shfl(incl, 63);
  int woff = 0;
  if (lane == 63) woff = atomicAdd(&sTot, total);
  woff = __shfl(woff, 63);
  __syncthreads();
  if (tid == 0) sBase = atomicAdd(&ecnt[b << 6], (unsigned int)sTot); // padded line
  __syncthreads();
  unsigned int pos = sBase + (unsigned int)(woff + incl - cnt);
  uint32_t* eb = edges + (size_t)b * ESLOTS;
  #define EMIT(mm, row) { ull e = (mm); while (e){ int bit = __builtin_ctzll(e); \
      e &= e - 1; eb[pos & EMASK] = ((uint32_t)(row) << 12) | (uint32_t)(base + bit); ++pos; } }
  #pragma unroll
  for (int r = 0; r < 4; ++r) EMIT(wl[r], i0 + r)
  #pragma unroll
  for (int r = 0; r < 4; ++r) EMIT(wh[r], h0 + r)
  #undef EMIT
}

// ---------------- K2: per-batch mega kernel --------------------------------
// cnt = sum(rcnt) (computed while seeding deg); start = ecnt[b] - cnt ->
// edges are DENSE at (start+d)&EMASK: no prefix scan, no binary search.
// P1 caches edges to LDS + j<i incidence; UF/labels/border on LDS edges.
// deg[i] = rcnt[i] + (#edges with col i); core <=> deg >= 2 (MIN_SAMPLES=3;
// self-pair always adjacent). P5 reads core roots from LAB (constant in P5).
__global__ __launch_bounds__(1024) void k_mega(const uint32_t* __restrict__ edges,
                                               const unsigned int* __restrict__ ecnt,
                                               const int* __restrict__ rcnt,
                                               uint32_t* __restrict__ spill,
                                               int* __restrict__ out){
  __shared__ int par[NPTS];          // deg -> UF parent -> A (counts)
  __shared__ int LAB[NPTS];
  __shared__ int Bb[NPTS];           // presence/ranks
  __shared__ unsigned char corea[NPTS];
  __shared__ uint32_t ec[ECACHE];    // dense edge cache
  __shared__ int wtots[16];
  __shared__ int sMost, sCnt;
  int b = blockIdx.x, t = threadIdx.x;
  int wid = t >> 6, lane = t & 63;
  const uint32_t* eb = edges + (size_t)b * ESLOTS;
  const int* rc = rcnt + (b << 12);
  uint32_t* sp = spill + (size_t)b * (ESLOTS - ECACHE);
  if (t == 0){ sMost = -1; sCnt = 0; }
  __syncthreads();
  // seed deg from rcnt (coalesced) + derive cnt = sum(rcnt)
  {
    int ls = 0;
    for (int s = 0; s < 4; ++s){ int v = (t << 2) + s; int x = rc[v]; par[v] = x; ls += x; }
    #pragma unroll
    for (int off = 32; off; off >>= 1) ls += __shfl_xor(ls, off);
    if (lane == 0) atomicAdd(&sCnt, ls);
  }
  __syncthreads();
  int cnt = sCnt;
  unsigned int start = ecnt[b << 6] - (unsigned int)cnt;  // mod 2^32 exact
  // P1: dense circular window -> LDS cache + j<i incidence, ONE pass
  for (int d = t; d < cnt; d += 1024){
    uint32_t pk = eb[(start + (unsigned int)d) & EMASK];
    if (d < ECACHE) ec[d] = pk; else sp[d - ECACHE] = pk;
    atomicAdd(&par[pk & 4095], 1);
  }
  __syncthreads();
  // P2: core flags, then reinit par as UF identity
  for (int s = 0; s < 4; ++s){ int v = (t << 2) + s; corea[v] = (par[v] >= 2) ? 1 : 0; }
  __syncthreads();
  for (int s = 0; s < 4; ++s){ int v = (t << 2) + s; par[v] = v; }
  __syncthreads();
  // P3: union core-core edges (single pass over dense LDS edges)
  for (int d = t; d < cnt; d += 1024){
    uint32_t pk = (d < ECACHE) ? ec[d] : sp[d - ECACHE];
    int u = pk >> 12, v = pk & 4095;
    if (corea[u] && corea[v]) union_lds(par, u, v);
  }
  __syncthreads();
  // P4: base labels (core: root; else SENT)
  for (int s = 0; s < 4; ++s){
    int v = (t << 2) + s;
    LAB[v] = corea[v] ? find_lds(par, v) : SENT;
  }
  __syncthreads();
  // P5: border relax — min core-neighbor ROOT read from LAB (no finds:
  // LAB[core] was finalized in P4 and is never written during P5)
  for (int d = t; d < cnt; d += 1024){
    uint32_t pk = (d < ECACHE) ? ec[d] : sp[d - ECACHE];
    int u = pk >> 12, v = pk & 4095;
    int cu = corea[u], cv = corea[v];
    if (cu && !cv)      atomicMin(&LAB[v], LAB[u]);
    else if (cv && !cu) atomicMin(&LAB[u], LAB[v]);
  }
  __syncthreads();
  // P6: finalize (noise fill, compact, cap). A aliases par (UF dead now).
  int* A = par;
  for (int s = 0; s < 4; ++s){ int v = (t << 2) + s; A[v] = 0; }
  __syncthreads();
  for (int s = 0; s < 4; ++s){ int l = LAB[(t << 2) + s]; if (l < SENT) atomicAdd(&A[l], 1); }
  __syncthreads();
  // most-common label: per-thread best -> wave shfl-max -> 1 atomic per wave
  {
    int best = -1;
    for (int s = 0; s < 4; ++s){
      int v = (t << 2) + s; int c = A[v];
      if (c > 0) best = max(best, (c << 13) | (4095 - v));  // tie -> smallest label
    }
    #pragma unroll
    for (int off = 32; off; off >>= 1) best = max(best, __shfl_xor(best, off));
    if (lane == 0 && best >= 0) atomicMax(&sMost, best);
  }
  __syncthreads();
  int most = (sMost >= 0) ? (4095 - (sMost & 8191)) : 0;
  for (int s = 0; s < 4; ++s){ int v = (t << 2) + s; if (LAB[v] == SENT) LAB[v] = most; Bb[v] = 0; }
  __syncthreads();
  for (int s = 0; s < 4; ++s) Bb[LAB[(t << 2) + s]] = 1;
  __syncthreads();
  // presence scan: wave shfl-scan + 16 wave totals -> rank = cumsum-1
  int pv[4]; int ls = 0;
  for (int s = 0; s < 4; ++s){ pv[s] = Bb[(t << 2) + s]; ls += pv[s]; }
  int incl = ls;
  #pragma unroll
  for (int off = 1; off < 64; off <<= 1){
    int y = __shfl_up(incl, off);
    if (lane >= off) incl += y;
  }
  if (lane == 63) wtots[wid] = incl;
  __syncthreads();
  int wbase = 0, ncl = 0;
  #pragma unroll
  for (int w = 0; w < 16; ++w){
    int wt = wtots[w];
    if (w < wid) wbase += wt;
    ncl += wt;
  }
  int run = wbase + incl - ls;
  for (int s = 0; s < 4; ++s){ run += pv[s]; Bb[(t << 2) + s] = run - 1; }
  __syncthreads();
  for (int s = 0; s < 4; ++s){ int v = (t << 2) + s; LAB[v] = Bb[LAB[v]]; }
  __syncthreads();
  if (ncl > MAXSP){
    // counts2 over compacted labels (0..ncl-1)
    for (int s = 0; s < 4; ++s) A[(t << 2) + s] = 0;
    __syncthreads();
    for (int s = 0; s < 4; ++s) atomicAdd(&A[LAB[(t << 2) + s]], 1);
    __syncthreads();
    // stable (count, index) rank over PRESENT labels only; absent labels
    // (count 0) occupy the first NPTS-ncl slots of the full argsort.
    for (int v = t; v < ncl; v += 1024){
      int keyv = A[v] * NPTS + v;
      int p = 0;
      for (int u = 0; u < ncl; ++u) p += ((A[u] * NPTS + u) < keyv) ? 1 : 0;
      int full = p + (NPTS - ncl);
      Bb[v] = (full >= NPTS - MAXSP) ? (full - (NPTS - MAXSP)) : 0;
    }
    __syncthreads();
    for (int s = 0; s < 4; ++s){ int v = (t << 2) + s; LAB[v] = Bb[LAB[v]]; }
    __syncthreads();
  }
  int* og = out + (b << 12);
  for (int s = 0; s < 4; ++s){ int v = (t << 2) + s; og[v] = LAB[v]; }
}

// ---------------- launch ----------------------------------------------------
extern "C" void kernel_launch(void* const* d_in, const int* in_sizes, int n_in,
                              void* d_out, int out_size, void* d_ws, size_t ws_size,
                              hipStream_t stream){
  const float* coords = (const float*)d_in[0];
  int* out = (int*)d_out;
  int batches = in_sizes[0] / (NPTS * 3);   // 8

  char* ws = (char*)d_ws;
  size_t off = 0;
  unsigned int* ecnt = (unsigned int*)(ws + off);
  off += (size_t)batches * 64 * sizeof(unsigned int); // padded 256B/batch; NEVER zeroed (mod-2^32 ticket)
  int* rcnt = (int*)(ws + off); off += (size_t)batches * NPTS * sizeof(int);    // 128KB
  uint32_t* edges = (uint32_t*)(ws + off); off += (size_t)batches * ESLOTS * sizeof(uint32_t); // 1MB
  uint32_t* spill = (uint32_t*)(ws + off); off += (size_t)batches * (ESLOTS - ECACHE) * sizeof(uint32_t);

  // K1: balanced triangle adjacency (LDS-staged) -> circular dense edges+rcnt
  //     32 adj blocks per batch (4 low + 4 high rows per wave x 16 waves)
  k_adj<<<batches * NSLICE, 1024, 0, stream>>>(coords, edges, ecnt, rcnt);
  // K2: per-batch mega (deg/core/UF/labels/border/finalize; dense edges)
  k_mega<<<batches, 1024, 0, stream>>>(edges, ecnt, rcnt, spill, out);
}